// Round 1
// baseline (110.356 us; speedup 1.0000x reference)
//
#include <hip/hip_runtime.h>

#define NATOMS 1024
#define BPB    128      // blocks per batch (row stride)
#define NB     32       // batches
#define BLK    256      // threads per block

// Stage 1: per-(batch, slot) partial sums over rows j = k, k+BPB, ...
// For row j we read B[b, j, i] for i in [0, j)  (strict lower triangle),
// which is exactly the reference's triu(i<j) of swapaxes(B,1,2).
__global__ __launch_bounds__(BLK) void reax_partial(
    const int*   __restrict__ Z,
    const float* __restrict__ B,
    const float* __restrict__ d0t,   // (3,3) row-major
    const float* __restrict__ p1t,
    const float* __restrict__ p2t,
    float*       __restrict__ ws)
{
    const int k   = blockIdx.x;   // slot within batch
    const int b   = blockIdx.y;   // batch
    const int tid = threadIdx.x;

    // pair-class tables: class s = t_i + t_j, with t = idx-1 in {0,1}
    // s=0 -> table[1][1], s=1 -> table[1][2], s=2 -> table[2][2]
    const float D0[3] = { d0t[4], d0t[5], d0t[8] };
    const float P1[3] = { p1t[4], p1t[5], p1t[8] };
    const float P2[3] = { p2t[4], p2t[5], p2t[8] };

    __shared__ unsigned char t_sh[NATOMS];
    const int* Zrow = Z + b * NATOMS;
    for (int i = tid; i < NATOMS; i += BLK)
        t_sh[i] = (Zrow[i] == 8) ? 1 : 0;
    __syncthreads();

    const float* Bb = B + (size_t)b * NATOMS * NATOMS;
    float sum = 0.0f;

    for (int j = k; j < NATOMS; j += BPB) {
        const int   tj  = t_sh[j];
        const float d0a = D0[tj],  d0b = D0[tj + 1];
        const float p1a = P1[tj],  p1b = P1[tj + 1];
        const float p2a = P2[tj],  p2b = P2[tj + 1];

        const float*  Brow  = Bb + (size_t)j * NATOMS;
        const float4* Brow4 = (const float4*)Brow;
        const int n  = j;        // elements in this row (i < j)
        const int nv = n >> 2;   // full float4 chunks

        for (int v = tid; v < nv; v += BLK) {
            const float4 x  = Brow4[v];
            const uchar4 tt = ((const uchar4*)t_sh)[v];

            #define ELEM(comp, tcomp)                                    \
            {                                                            \
                const float bb = fabsf(x.comp);                          \
                const int   ti = (int)tt.tcomp;                          \
                const float p2 = ti ? p2b : p2a;                         \
                const float p1 = ti ? p1b : p1a;                         \
                const float d0 = ti ? d0b : d0a;                         \
                const float pw = __powf(bb, p2);                         \
                const float ex = __expf(fmaf(-p1, pw, p1));              \
                sum = fmaf(d0 * bb, ex, sum);                            \
            }
            ELEM(x, x) ELEM(y, y) ELEM(z, z) ELEM(w, w)
            #undef ELEM
        }
        // tail: up to 3 scalar elements
        const int i = (nv << 2) + tid;
        if (i < n) {
            const float bb = fabsf(Brow[i]);
            const int   ti = (int)t_sh[i];
            const float p2 = ti ? p2b : p2a;
            const float p1 = ti ? p1b : p1a;
            const float d0 = ti ? d0b : d0a;
            const float pw = __powf(bb, p2);
            const float ex = __expf(fmaf(-p1, pw, p1));
            sum = fmaf(d0 * bb, ex, sum);
        }
    }

    // block reduction: wave shuffle then LDS across 4 waves
    #pragma unroll
    for (int off = 32; off; off >>= 1) sum += __shfl_down(sum, off, 64);
    __shared__ float wsum[BLK / 64];
    if ((tid & 63) == 0) wsum[tid >> 6] = sum;
    __syncthreads();
    if (tid == 0)
        ws[b * BPB + k] = wsum[0] + wsum[1] + wsum[2] + wsum[3];
}

// Stage 2: one 64-lane wave per batch reduces the BPB partials.
__global__ __launch_bounds__(64) void reax_reduce(
    const float* __restrict__ ws, float* __restrict__ out)
{
    const int b = blockIdx.x;
    const int t = threadIdx.x;
    float s = ws[b * BPB + t] + ws[b * BPB + t + 64];
    #pragma unroll
    for (int off = 32; off; off >>= 1) s += __shfl_down(s, off, 64);
    if (t == 0) out[b] = -s;   // e_ij carries a leading minus sign
}

extern "C" void kernel_launch(void* const* d_in, const int* in_sizes, int n_in,
                              void* d_out, int out_size, void* d_ws, size_t ws_size,
                              hipStream_t stream) {
    const int*   Z   = (const int*)  d_in[0];
    const float* B   = (const float*)d_in[1];
    const float* d0t = (const float*)d_in[2];
    const float* p1t = (const float*)d_in[3];
    const float* p2t = (const float*)d_in[4];
    float* out = (float*)d_out;
    float* ws  = (float*)d_ws;   // NB*BPB floats, fully rewritten every call

    dim3 grid(BPB, NB);
    reax_partial<<<grid, BLK, 0, stream>>>(Z, B, d0t, p1t, p2t, ws);
    reax_reduce<<<NB, 64, 0, stream>>>(ws, out);
}

// Round 2
// 102.438 us; speedup vs baseline: 1.0773x; 1.0773x over previous
//
#include <hip/hip_runtime.h>

#define NATOMS 1024
#define NB     32
#define WPB    4                 // waves per block
#define BLK    (WPB * 64)        // 256 threads
#define BPBATCH 32               // blocks per batch
#define WAVES  (BPBATCH * WPB)   // 128 waves per batch
#define PAIRS  (NATOMS / 2)      // 512 row-pairs per batch
#define PPW    (PAIRS / WAVES)   // 4 pairs per wave

// Stage 1: each wave processes PPW row-pairs (rows p and 1023-p -> constant
// 1023 elements per pair, perfect balance). Row j's strict prefix i<j of
// B[b,j,:] is read with coalesced float4, one full wave per 256 elements.
__global__ __launch_bounds__(BLK) void reax_partial(
    const int*   __restrict__ Z,
    const float* __restrict__ B,
    const float* __restrict__ d0t,
    const float* __restrict__ p1t,
    const float* __restrict__ p2t,
    float*       __restrict__ ws)
{
    const int b    = blockIdx.y;
    const int wave = blockIdx.x * WPB + (threadIdx.x >> 6);
    const int lane = threadIdx.x & 63;

    // pair-class tables: s = t_i + t_j in {0,1,2} -> table[1][1],[1][2],[2][2]
    const float D0s0 = d0t[4], D0s1 = d0t[5], D0s2 = d0t[8];
    const float P1s0 = p1t[4], P1s1 = p1t[5], P1s2 = p1t[8];
    const float P2s0 = p2t[4], P2s1 = p2t[5], P2s2 = p2t[8];

    __shared__ unsigned char t_sh[NATOMS];
    const int* Zrow = Z + b * NATOMS;
    for (int i = threadIdx.x; i < NATOMS; i += BLK)
        t_sh[i] = (Zrow[i] == 8) ? 1 : 0;
    __syncthreads();

    const float* Bb = B + (size_t)b * NATOMS * NATOMS;
    float sum = 0.0f;

    for (int pp = 0; pp < PPW; ++pp) {
        const int p = wave + pp * WAVES;   // 0..511
        #pragma unroll
        for (int r = 0; r < 2; ++r) {
            const int j = r ? (NATOMS - 1 - p) : p;
            if (j == 0) continue;
            const int tj = (int)t_sh[j];
            // params are linear in ti: param = base + ti * delta
            const float d0a = tj ? D0s1 : D0s0, dd0 = tj ? (D0s2 - D0s1) : (D0s1 - D0s0);
            const float p1a = tj ? P1s1 : P1s0, dp1 = tj ? (P1s2 - P1s1) : (P1s1 - P1s0);
            const float p2a = tj ? P2s1 : P2s0, dp2 = tj ? (P2s2 - P2s1) : (P2s1 - P2s0);

            const float*  Brow  = Bb + (size_t)j * NATOMS;
            const float4* Brow4 = (const float4*)Brow;
            const int nv = j >> 2;

            for (int v = lane; v < nv; v += 64) {
                const float4 x  = Brow4[v];
                const uchar4 tt = ((const uchar4*)t_sh)[v];

                #define ELEM(xc, tc)                                        \
                {                                                           \
                    const float tif = (float)(tc);                          \
                    const float bb  = fabsf(xc);                            \
                    const float p2  = fmaf(tif, dp2, p2a);                  \
                    const float p1  = fmaf(tif, dp1, p1a);                  \
                    const float d0  = fmaf(tif, dd0, d0a);                  \
                    const float pw  = __powf(bb, p2);                       \
                    const float ex  = __expf(fmaf(-p1, pw, p1));            \
                    sum = fmaf(d0 * bb, ex, sum);                           \
                }
                ELEM(x.x, tt.x) ELEM(x.y, tt.y) ELEM(x.z, tt.z) ELEM(x.w, tt.w)
                #undef ELEM
            }
            // tail: up to 3 elements
            const int i = (nv << 2) + lane;
            if (i < j) {
                const float tif = (float)t_sh[i];
                const float bb  = fabsf(Brow[i]);
                const float p2  = fmaf(tif, dp2, p2a);
                const float p1  = fmaf(tif, dp1, p1a);
                const float d0  = fmaf(tif, dd0, d0a);
                const float pw  = __powf(bb, p2);
                const float ex  = __expf(fmaf(-p1, pw, p1));
                sum = fmaf(d0 * bb, ex, sum);
            }
        }
    }

    // wave reduction; one write per wave (no cross-wave LDS pass needed)
    #pragma unroll
    for (int off = 32; off; off >>= 1) sum += __shfl_down(sum, off, 64);
    if (lane == 0) ws[b * WAVES + wave] = sum;
}

// Stage 2: one 64-lane wave per batch reduces the WAVES partials.
__global__ __launch_bounds__(64) void reax_reduce(
    const float* __restrict__ ws, float* __restrict__ out)
{
    const int b = blockIdx.x;
    const int t = threadIdx.x;
    float s = ws[b * WAVES + t] + ws[b * WAVES + t + 64];
    #pragma unroll
    for (int off = 32; off; off >>= 1) s += __shfl_down(s, off, 64);
    if (t == 0) out[b] = -s;   // e_ij carries the leading minus sign
}

extern "C" void kernel_launch(void* const* d_in, const int* in_sizes, int n_in,
                              void* d_out, int out_size, void* d_ws, size_t ws_size,
                              hipStream_t stream) {
    const int*   Z   = (const int*)  d_in[0];
    const float* B   = (const float*)d_in[1];
    const float* d0t = (const float*)d_in[2];
    const float* p1t = (const float*)d_in[3];
    const float* p2t = (const float*)d_in[4];
    float* out = (float*)d_out;
    float* ws  = (float*)d_ws;   // NB*WAVES floats, fully rewritten every call

    dim3 grid(BPBATCH, NB);
    reax_partial<<<grid, BLK, 0, stream>>>(Z, B, d0t, p1t, p2t, ws);
    reax_reduce<<<NB, 64, 0, stream>>>(ws, out);
}

// Round 3
// 22.433 us; speedup vs baseline: 4.9193x; 4.5664x over previous
//
#include <hip/hip_runtime.h>

#define NATOMS  1024
#define NB      32
#define WPB     4                  // waves per block
#define BLK     (WPB * 64)         // 256 threads
#define BPBATCH 64                 // blocks per batch
#define WAVES   (BPBATCH * WPB)    // 256 waves per batch
#define PPW     ((NATOMS / 2) / WAVES)  // 2 row-pairs per wave

// Stage 1: each wave processes PPW row-pairs (rows p and 1023-p -> constant
// 1023 elements/pair). Row j's strict prefix i<j of B[b,j,:] is read with
// coalesced float4. All transcendentals are forced to native v_log_f32 /
// v_exp_f32 via __builtin_amdgcn_{logf,exp2f}:
//   e = d0*b*exp(p1*(1-b^p2)) = (d0*e^p1) * b * exp2(c1 * exp2(p2*log2 b)),
//   c1 = -p1*log2(e).
__global__ __launch_bounds__(BLK) void reax_partial(
    const int*   __restrict__ Z,
    const float* __restrict__ B,
    const float* __restrict__ d0t,
    const float* __restrict__ p1t,
    const float* __restrict__ p2t,
    float*       __restrict__ ws)
{
    const int b    = blockIdx.y;
    const int wave = blockIdx.x * WPB + (threadIdx.x >> 6);
    const int lane = threadIdx.x & 63;

    const float LOG2E = 1.4426950408889634f;
    // pair-class s = t_i + t_j in {0,1,2} -> table[1][1], [1][2], [2][2]
    const float d0_0 = d0t[4], d0_1 = d0t[5], d0_2 = d0t[8];
    const float p1_0 = p1t[4], p1_1 = p1t[5], p1_2 = p1t[8];
    const float p2_0 = p2t[4], p2_1 = p2t[5], p2_2 = p2t[8];
    const float de_0 = d0_0 * __builtin_amdgcn_exp2f(p1_0 * LOG2E);
    const float de_1 = d0_1 * __builtin_amdgcn_exp2f(p1_1 * LOG2E);
    const float de_2 = d0_2 * __builtin_amdgcn_exp2f(p1_2 * LOG2E);
    const float c1_0 = -p1_0 * LOG2E, c1_1 = -p1_1 * LOG2E, c1_2 = -p1_2 * LOG2E;

    __shared__ unsigned char t_sh[NATOMS];
    const int* Zrow = Z + b * NATOMS;
    for (int i = threadIdx.x; i < NATOMS; i += BLK)
        t_sh[i] = (Zrow[i] == 8) ? 1 : 0;
    __syncthreads();

    const float* Bb = B + (size_t)b * NATOMS * NATOMS;
    float sum0 = 0.0f, sum1 = 0.0f;

    for (int pp = 0; pp < PPW; ++pp) {
        const int p = wave + pp * WAVES;   // 0..511
        #pragma unroll
        for (int r = 0; r < 2; ++r) {
            const int j = r ? (NATOMS - 1 - p) : p;
            if (j == 0) continue;
            const int tj = (int)t_sh[j];
            // per-row class params, linear in t_i: val = a + t_i * delta
            const float dea = tj ? de_1 : de_0, dde = tj ? (de_2 - de_1) : (de_1 - de_0);
            const float c1a = tj ? c1_1 : c1_0, dc1 = tj ? (c1_2 - c1_1) : (c1_1 - c1_0);
            const float p2a = tj ? p2_1 : p2_0, dp2 = tj ? (p2_2 - p2_1) : (p2_1 - p2_0);

            const float*  Brow  = Bb + (size_t)j * NATOMS;
            const float4* Brow4 = (const float4*)Brow;
            const int nv = j >> 2;

            for (int v = lane; v < nv; v += 64) {
                const float4 x  = Brow4[v];
                const uchar4 tt = ((const uchar4*)t_sh)[v];

                #define ELEM(xc, tc, acc)                                   \
                {                                                           \
                    const float tif = (float)(tc);                          \
                    const float bb  = fabsf(xc);                            \
                    const float p2  = fmaf(tif, dp2, p2a);                  \
                    const float c1  = fmaf(tif, dc1, c1a);                  \
                    const float de  = fmaf(tif, dde, dea);                  \
                    const float lg  = __builtin_amdgcn_logf(bb);            \
                    const float pw  = __builtin_amdgcn_exp2f(p2 * lg);      \
                    const float ex  = __builtin_amdgcn_exp2f(c1 * pw);      \
                    acc = fmaf(de * bb, ex, acc);                           \
                }
                ELEM(x.x, tt.x, sum0) ELEM(x.y, tt.y, sum1)
                ELEM(x.z, tt.z, sum0) ELEM(x.w, tt.w, sum1)
                #undef ELEM
            }
            // tail: up to 3 elements
            const int i = (nv << 2) + lane;
            if (i < j) {
                const float tif = (float)t_sh[i];
                const float bb  = fabsf(Brow[i]);
                const float p2  = fmaf(tif, dp2, p2a);
                const float c1  = fmaf(tif, dc1, c1a);
                const float de  = fmaf(tif, dde, dea);
                const float lg  = __builtin_amdgcn_logf(bb);
                const float pw  = __builtin_amdgcn_exp2f(p2 * lg);
                const float ex  = __builtin_amdgcn_exp2f(c1 * pw);
                sum0 = fmaf(de * bb, ex, sum0);
            }
        }
    }

    float sum = sum0 + sum1;
    #pragma unroll
    for (int off = 32; off; off >>= 1) sum += __shfl_down(sum, off, 64);
    if (lane == 0) ws[b * WAVES + wave] = sum;
}

// Stage 2: one 64-lane wave per batch reduces the WAVES partials.
__global__ __launch_bounds__(64) void reax_reduce(
    const float* __restrict__ ws, float* __restrict__ out)
{
    const int b = blockIdx.x;
    const int t = threadIdx.x;
    float s = ws[b * WAVES + t]       + ws[b * WAVES + t + 64]
            + ws[b * WAVES + t + 128] + ws[b * WAVES + t + 192];
    #pragma unroll
    for (int off = 32; off; off >>= 1) s += __shfl_down(s, off, 64);
    if (t == 0) out[b] = -s;   // e_ij carries the leading minus sign
}

extern "C" void kernel_launch(void* const* d_in, const int* in_sizes, int n_in,
                              void* d_out, int out_size, void* d_ws, size_t ws_size,
                              hipStream_t stream) {
    const int*   Z   = (const int*)  d_in[0];
    const float* B   = (const float*)d_in[1];
    const float* d0t = (const float*)d_in[2];
    const float* p1t = (const float*)d_in[3];
    const float* p2t = (const float*)d_in[4];
    float* out = (float*)d_out;
    float* ws  = (float*)d_ws;   // NB*WAVES floats, fully rewritten every call

    dim3 grid(BPBATCH, NB);
    reax_partial<<<grid, BLK, 0, stream>>>(Z, B, d0t, p1t, p2t, ws);
    reax_reduce<<<NB, 64, 0, stream>>>(ws, out);
}